// Round 14
// baseline (5199.919 us; speedup 1.0000x reference)
//
#include <hip/hip_runtime.h>

#define NB    16      // batches
#define NPTS  100000  // points per batch
#define NCH   16      // channels
#define KSEL  1024    // samples
#define SLOTS 16      // blocks per batch
#define TPB   256     // threads per block
#define CHUNK 6250    // NPTS / SLOTS
#define PPT   25      // CHUNK / TPB
#define MAGA  0x19u   // 5-bit magic, key words    (never 0, never 0xAA-pattern)
#define MAGB  0x13u   // 5-bit magic, payload words

typedef unsigned long long u64;
typedef unsigned int u32;

// d_ws layout (bytes):
//   [0,     32)    : per-XCD rank counters int[8]
//   [64,    1088)  : claim flags int[256]  (one per (batch,slot))
//   [4096,  20480) : FAST tier  u64[par=2][NB][word=4][slot=16]
//                    plain (workgroup-scope) stores -> DIRTY line in local XCD L2;
//                    readers: agent-acquire fence (buffer_inv, drops CLEAN lines
//                    only) + plain load -> hits the dirty line L2-locally.
//   [20480, 36864) : SLOW tier  same layout, agent-scope atomics (device-coherent)
//   [65536, 131072): idx list int[NB][KSEL]
//
// key     = val_bits(32) | invidx(17) | tag(10) | MAGA(5)   (u64 max == winner)
// payload = coord_bits(32) | invidx(17) | tag(10) | MAGB(5)
// invidx = 131071 - idx (max invidx == min idx -> first-index tie-break).
// tag = i+1 (never 0 -> memset-0 / 0xAA never match). Tag+magic in EVERY u64 ->
// stale/torn/poison self-rejecting; records deterministic per (slot, iter) ->
// any stale path (incl. cross-replay residue) is value-correct. Parity
// double-buffer prevents overwrite-before-read.
//
// Placement: observed dispatch = 1 block/CU for 256-block grids (Occupancy
// ~12.5% in r5-r13) -> 32 blocks/XCD; XCC_ID-pool claiming gives every batch
// 16 same-XCD blocks. If packing ever differs, overflow claims scatter and
// those batches ride the SLOW tier (every 8th retry) = r8 behavior. Output
// identical regardless of placement.

__device__ __forceinline__ void combine(float ov, int oi, float& v, int& i) {
  if (ov > v || (ov == v && oi < i)) { v = ov; i = oi; }
}

__global__ __launch_bounds__(TPB, 1)
void fps_kernel(const float* __restrict__ points, const int* __restrict__ start_idx,
                int* __restrict__ ws_cnt, int* __restrict__ ws_claim,
                u64* __restrict__ ws_fast, u64* __restrict__ ws_slow,
                int* __restrict__ ws_idx) {
  const int tid  = threadIdx.x;
  const int lane = tid & 63;
  const int wid  = tid >> 6;

  // ---- claim a (batch, slot) from this XCD's pool ----
  __shared__ int s_bs;
  if (tid == 0) {
    u32 xcd;
    asm volatile("s_getreg_b32 %0, hwreg(HW_REG_XCC_ID, 0, 32)" : "=s"(xcd));
    xcd &= 7u;
    const int rank = __hip_atomic_fetch_add(ws_cnt + xcd, 1, __ATOMIC_RELAXED,
                                            __HIP_MEMORY_SCOPE_AGENT);
    int got = -1;
    if (rank < 32) {
      const int pref = (int)xcd * 32 + rank;      // unique per (xcd,rank)
      if (__hip_atomic_exchange(ws_claim + pref, 1, __ATOMIC_RELAXED,
                                __HIP_MEMORY_SCOPE_AGENT) == 0)
        got = pref;
    }
    for (int j = 0; got < 0 && j < 256; ++j)      // pigeonhole: always succeeds
      if (__hip_atomic_exchange(ws_claim + j, 1, __ATOMIC_RELAXED,
                                __HIP_MEMORY_SCOPE_AGENT) == 0)
        got = j;
    s_bs = got;
  }
  __syncthreads();
  const int b    = s_bs >> 4;
  const int slot = s_bs & 15;

  const int base = slot * CHUNK;
  const float* __restrict__ pb = points + (size_t)b * NPTS * NCH;

  // ---- load xyz into registers, init min_d ----
  float px[PPT], py[PPT], pz[PPT], md[PPT];
  #pragma unroll
  for (int k = 0; k < PPT; ++k) {
    const int li = tid + (k << 8);
    const bool valid = li < CHUNK;
    float4 p = make_float4(0.f, 0.f, 0.f, 0.f);
    if (valid) p = *reinterpret_cast<const float4*>(pb + (size_t)(base + li) * NCH);
    px[k] = p.x; py[k] = p.y; pz[k] = p.z;
    md[k] = valid ? __builtin_inff() : -__builtin_inff();
  }
  #pragma unroll
  for (int k = 0; k < PPT; ++k)   // keep-live guard
    asm volatile("" : "+v"(px[k]), "+v"(py[k]), "+v"(pz[k]), "+v"(md[k]));

  __shared__ float s_rv[4];            // per-wave candidates (b1-protected)
  __shared__ int   s_ri[4];
  __shared__ float s_wx, s_wy, s_wz;   // winner broadcast (b2-protected)

  // ---- initial selected point ----
  const int sidx = start_idx[b];
  float sx, sy, sz;
  {
    const float4 p = *reinterpret_cast<const float4*>(pb + (size_t)sidx * NCH);
    sx = p.x; sy = p.y; sz = p.z;
  }
  if (slot == 0 && tid == 0) ws_idx[b * KSEL] = sidx;

  for (int i = 0; i < KSEL - 1; ++i) {
    const int par = i & 1;
    u64* const fblk = ws_fast + (((size_t)par * NB + b) << 6);  // 64 u64
    u64* const sblk = ws_slow + (((size_t)par * NB + b) << 6);

    // ---- distance update + thread-local argmax (bit-exact vs numpy f32:
    //      IEEE intrinsics, left-to-right sum, no FMA contraction) ----
    float bv = -__builtin_inff();
    int   bi = 0x7fffffff;
    #pragma unroll
    for (int k = 0; k < PPT; ++k) {
      const float dx = __fsub_rn(px[k], sx);
      const float dy = __fsub_rn(py[k], sy);
      const float dz = __fsub_rn(pz[k], sz);
      const float d  = __fadd_rn(__fadd_rn(__fmul_rn(dx, dx), __fmul_rn(dy, dy)),
                                 __fmul_rn(dz, dz));
      const float m  = fminf(md[k], d);
      md[k] = m;
      if (m > bv) { bv = m; bi = base + tid + (k << 8); }  // k asc -> first-max kept
    }

    // ---- wave reduce (val, idx), first-index tie-break ----
    #pragma unroll
    for (int m = 32; m >= 1; m >>= 1) {
      const float ov = __shfl_xor(bv, m, 64);
      const int   oi = __shfl_xor(bi, m, 64);
      combine(ov, oi, bv, bi);
    }
    if (lane == 0) { s_rv[wid] = bv; s_ri[wid] = bi; }
    __syncthreads();                                   // b1: candidates ready

    // ---- block combine (every thread) ----
    bv = s_rv[0]; bi = s_ri[0];
    #pragma unroll
    for (int w = 1; w < 4; ++w) combine(s_rv[w], s_ri[w], bv, bi);

    const u32 tm = (u32)(i + 1) << 5;

    // ---- owner thread publishes {key,x,y,z}: FAST (plain -> dirty in local
    //      L2) first, then SLOW (agent) insurance; no waits in between ----
    const int local = bi - base;
    if (tid == (local & 255)) {
      const int kk = local >> 8;
      float ox = 0.f, oy = 0.f, oz = 0.f;
      #pragma unroll
      for (int k = 0; k < PPT; ++k)   // static-index select (arrays stay in VGPRs)
        if (k == kk) { ox = px[k]; oy = py[k]; oz = pz[k]; }
      const u32 inv = 131071u - (u32)bi;
      const u64 w0 = ((u64)__float_as_uint(bv) << 32) | (inv << 15) | tm | MAGA;
      const u64 mt = (u64)((inv << 15) | tm | MAGB);
      const u64 w1 = ((u64)__float_as_uint(ox) << 32) | mt;
      const u64 w2 = ((u64)__float_as_uint(oy) << 32) | mt;
      const u64 w3 = ((u64)__float_as_uint(oz) << 32) | mt;
      __hip_atomic_store(fblk      + slot, w0, __ATOMIC_RELAXED, __HIP_MEMORY_SCOPE_WORKGROUP);
      __hip_atomic_store(fblk + 16 + slot, w1, __ATOMIC_RELAXED, __HIP_MEMORY_SCOPE_WORKGROUP);
      __hip_atomic_store(fblk + 32 + slot, w2, __ATOMIC_RELAXED, __HIP_MEMORY_SCOPE_WORKGROUP);
      __hip_atomic_store(fblk + 48 + slot, w3, __ATOMIC_RELAXED, __HIP_MEMORY_SCOPE_WORKGROUP);
      __hip_atomic_store(sblk      + slot, w0, __ATOMIC_RELAXED, __HIP_MEMORY_SCOPE_AGENT);
      __hip_atomic_store(sblk + 16 + slot, w1, __ATOMIC_RELAXED, __HIP_MEMORY_SCOPE_AGENT);
      __hip_atomic_store(sblk + 32 + slot, w2, __ATOMIC_RELAXED, __HIP_MEMORY_SCOPE_AGENT);
      __hip_atomic_store(sblk + 48 + slot, w3, __ATOMIC_RELAXED, __HIP_MEMORY_SCOPE_AGENT);
    }

    // ---- wave 0 ONLY polls: {agent-acquire fence (buffer_inv: drops clean
    //      lines, keeps dirty) + plain load} -> local-L2 hit when same-XCD;
    //      agent-tier insurance every 8th retry ----
    if (wid == 0) {
      const int  word = lane >> 4;                 // 0=key,1=x,2=y,3=z
      const u32  want = tm | (word == 0 ? MAGA : MAGB);
      u64 q = 0;
      bool got = false;
      int r = 0;
      for (;;) {
        __builtin_amdgcn_fence(__ATOMIC_ACQUIRE, "agent");   // vmcnt drain + buffer_inv
        if (!got) {
          const u64 t = __hip_atomic_load(fblk + lane, __ATOMIC_RELAXED,
                                          __HIP_MEMORY_SCOPE_WORKGROUP);
          if (((u32)t & 0x7FFFu) == want) { q = t; got = true; }
        }
        if (__all(got)) break;
        if (!got && ((++r & 7) == 0)) {            // insurance: coherent tier
          const u64 t = __hip_atomic_load(sblk + lane, __ATOMIC_RELAXED,
                                          __HIP_MEMORY_SCOPE_AGENT);
          if (((u32)t & 0x7FFFu) == want) { q = t; got = true; }
        }
      }
      // max over the 16 key lanes (xor net closed within each 16-group)
      u64 key = (word == 0) ? q : 0;
      #pragma unroll
      for (int m = 8; m >= 1; m >>= 1) {
        const u64 o = __shfl_xor(key, m, 64);
        if (o > key) key = o;
      }
      const u64 kmax = __shfl(key, 0, 64);         // broadcast winner key
      const unsigned long long ball = __ballot(word == 0 && q == kmax);
      const int rs = __ffsll(ball) - 1;            // winning slot (keys unique)
      const u32 hi = (u32)(q >> 32);
      const u32 xb = (u32)__shfl((int)hi, 16 + rs, 64);
      const u32 yb = (u32)__shfl((int)hi, 32 + rs, 64);
      const u32 zb = (u32)__shfl((int)hi, 48 + rs, 64);
      if (lane == 0) {
        s_wx = __uint_as_float(xb);
        s_wy = __uint_as_float(yb);
        s_wz = __uint_as_float(zb);
        if (slot == 0)
          ws_idx[b * KSEL + i + 1] = 131071 - (int)((kmax >> 15) & 0x1FFFFu);
      }
    }
    __syncthreads();                                   // b2: winner ready
    sx = s_wx; sy = s_wy; sz = s_wz;
  }
}

__global__ void gather_kernel(const float* __restrict__ points,
                              const int* __restrict__ ws_idx,
                              float* __restrict__ out) {
  const int e = blockIdx.x * 256 + threadIdx.x;   // 0 .. NB*KSEL*NCH-1
  const int c = e & 15;
  const int k = (e >> 4) & (KSEL - 1);
  const int b = e >> 14;
  const int idx = ws_idx[b * KSEL + k];
  out[e] = points[((size_t)b * NPTS + idx) * NCH + c];
}

extern "C" void kernel_launch(void* const* d_in, const int* in_sizes, int n_in,
                              void* d_out, int out_size, void* d_ws, size_t ws_size,
                              hipStream_t stream) {
  const float* points    = (const float*)d_in[0];
  const int*   start_idx = (const int*)d_in[1];
  float*       out       = (float*)d_out;

  int* cnt   = (int*)d_ws;
  int* claim = (int*)((char*)d_ws + 64);
  u64* fast  = (u64*)((char*)d_ws + 4096);
  u64* slow  = (u64*)((char*)d_ws + 20480);
  int* idxl  = (int*)((char*)d_ws + 65536);

  // counters, claims, and all record words start 0 every launch (graph-replay safe)
  hipMemsetAsync(d_ws, 0, 36864, stream);

  fps_kernel<<<NB * SLOTS, TPB, 0, stream>>>(points, start_idx, cnt, claim, fast, slow, idxl);
  gather_kernel<<<(NB * KSEL * NCH) / 256, 256, 0, stream>>>(points, idxl, out);
}

// Round 15
// 4662.863 us; speedup vs baseline: 1.1152x; 1.1152x over previous
//
#include <hip/hip_runtime.h>

#define NB    16      // batches
#define NPTS  100000  // points per batch
#define NCH   16      // channels
#define KSEL  1024    // samples
#define SLOTS 16      // blocks per batch
#define TPB   256     // threads per block
#define CHUNK 6250    // NPTS / SLOTS
#define PPT   25      // CHUNK / TPB
#define MAGA  0x19u   // 5-bit magic, key words    (never 0, never 0xAA-pattern)
#define MAGB  0x13u   // 5-bit magic, payload words

typedef unsigned long long u64;
typedef unsigned int u32;

// d_ws layout (bytes):
//   [4096, 20480)  : records u64[par=2][NB][slot=16][word=4]   (AoS: one 32B
//                    record per slot; a (par,b) region = 512B = 4 lines; the 4
//                    publish stores land in ONE line)
//   [65536, 131072): idx list int[NB][KSEL]
//
// word0 key = val_bits(32) | invidx(17) | tag(10) | MAGA(5)   (u64 max == winner)
// word1..3  = coord_bits(32) | invidx(17) | tag(10) | MAGB(5)  (x,y,z)
// invidx = 131071 - idx (max invidx == min idx -> first-index tie-break).
// tag = i+1 (1..1023, never 0 -> memset-0 / 0xAA never match). Tag+magic in
// EVERY u64 -> stale/torn/poison self-rejecting. Single writer per
// (slot,parity,tag); parity double-buffer prevents overwrite-before-read
// (a writer reaches tag i+2 only after all readers consumed tag i).
// Contention design (r8-proven): ONE polling wave per block (16/batch);
// poll = 1 u64 agent load per lane, 2-deep pipelined (sampling ~RTT/2).

__device__ __forceinline__ void combine(float ov, int oi, float& v, int& i) {
  if (ov > v || (ov == v && oi < i)) { v = ov; i = oi; }
}

__global__ __launch_bounds__(TPB, 1)
void fps_kernel(const float* __restrict__ points, const int* __restrict__ start_idx,
                u64* __restrict__ ws_cand, int* __restrict__ ws_idx) {
  // XCD-affinity swizzle (harmless; L2 locality for input reads)
  const int raw  = blockIdx.x;
  const int xcd  = raw & 7;
  const int s    = raw >> 3;
  const int b    = xcd + 8 * (s >> 4);
  const int slot = s & 15;

  const int tid  = threadIdx.x;
  const int lane = tid & 63;
  const int wid  = tid >> 6;

  const int base = slot * CHUNK;
  const float* __restrict__ pb = points + (size_t)b * NPTS * NCH;

  // ---- load xyz into registers, init min_d ----
  float px[PPT], py[PPT], pz[PPT], md[PPT];
  #pragma unroll
  for (int k = 0; k < PPT; ++k) {
    const int li = tid + (k << 8);
    const bool valid = li < CHUNK;
    float4 p = make_float4(0.f, 0.f, 0.f, 0.f);
    if (valid) p = *reinterpret_cast<const float4*>(pb + (size_t)(base + li) * NCH);
    px[k] = p.x; py[k] = p.y; pz[k] = p.z;
    md[k] = valid ? __builtin_inff() : -__builtin_inff();
  }
  #pragma unroll
  for (int k = 0; k < PPT; ++k)   // keep-live guard
    asm volatile("" : "+v"(px[k]), "+v"(py[k]), "+v"(pz[k]), "+v"(md[k]));

  __shared__ float s_rv[4];            // per-wave candidates (b1-protected)
  __shared__ int   s_ri[4];
  __shared__ float s_wx, s_wy, s_wz;   // winner broadcast (b2-protected)

  // ---- initial selected point ----
  const int sidx = start_idx[b];
  float sx, sy, sz;
  {
    const float4 p = *reinterpret_cast<const float4*>(pb + (size_t)sidx * NCH);
    sx = p.x; sy = p.y; sz = p.z;
  }
  if (slot == 0 && tid == 0) ws_idx[b * KSEL] = sidx;

  for (int i = 0; i < KSEL - 1; ++i) {
    const int par = i & 1;
    u64* const blk = ws_cand + (((size_t)par * NB + b) << 6);  // 64 u64 per (par,b)

    // ---- distance update + thread-local argmax (bit-exact vs numpy f32:
    //      IEEE intrinsics, left-to-right sum, no FMA contraction) ----
    float bv = -__builtin_inff();
    int   bi = 0x7fffffff;
    #pragma unroll
    for (int k = 0; k < PPT; ++k) {
      const float dx = __fsub_rn(px[k], sx);
      const float dy = __fsub_rn(py[k], sy);
      const float dz = __fsub_rn(pz[k], sz);
      const float d  = __fadd_rn(__fadd_rn(__fmul_rn(dx, dx), __fmul_rn(dy, dy)),
                                 __fmul_rn(dz, dz));
      const float m  = fminf(md[k], d);
      md[k] = m;
      if (m > bv) { bv = m; bi = base + tid + (k << 8); }  // k asc -> first-max kept
    }

    // ---- wave reduce (val, idx), first-index tie-break ----
    #pragma unroll
    for (int m = 32; m >= 1; m >>= 1) {
      const float ov = __shfl_xor(bv, m, 64);
      const int   oi = __shfl_xor(bi, m, 64);
      combine(ov, oi, bv, bi);
    }
    if (lane == 0) { s_rv[wid] = bv; s_ri[wid] = bi; }
    __syncthreads();                                   // b1: candidates ready

    // ---- block combine (every thread) ----
    bv = s_rv[0]; bi = s_ri[0];
    #pragma unroll
    for (int w = 1; w < 4; ++w) combine(s_rv[w], s_ri[w], bv, bi);

    const u32 tm = (u32)(i + 1) << 5;

    // ---- owner thread publishes the 32B AoS record (4 stores, ONE line) ----
    const int local = bi - base;
    if (tid == (local & 255)) {
      const int kk = local >> 8;
      float ox = 0.f, oy = 0.f, oz = 0.f;
      #pragma unroll
      for (int k = 0; k < PPT; ++k)   // static-index select (arrays stay in VGPRs)
        if (k == kk) { ox = px[k]; oy = py[k]; oz = pz[k]; }
      const u32 inv = 131071u - (u32)bi;
      u64* const rec = blk + ((size_t)slot << 2);
      const u64 mt = (u64)((inv << 15) | tm | MAGB);
      __hip_atomic_store(rec + 0, ((u64)__float_as_uint(bv) << 32) | (inv << 15) | tm | MAGA,
                         __ATOMIC_RELAXED, __HIP_MEMORY_SCOPE_AGENT);
      __hip_atomic_store(rec + 1, ((u64)__float_as_uint(ox) << 32) | mt,
                         __ATOMIC_RELAXED, __HIP_MEMORY_SCOPE_AGENT);
      __hip_atomic_store(rec + 2, ((u64)__float_as_uint(oy) << 32) | mt,
                         __ATOMIC_RELAXED, __HIP_MEMORY_SCOPE_AGENT);
      __hip_atomic_store(rec + 3, ((u64)__float_as_uint(oz) << 32) | mt,
                         __ATOMIC_RELAXED, __HIP_MEMORY_SCOPE_AGENT);
    }

    // ---- wave 0 ONLY polls; 2-deep pipelined sampling (no sleep) ----
    if (wid == 0) {
      const int  word = lane & 3;                  // AoS: lane = slot*4 + word
      const u32  want = tm | (word == 0 ? MAGA : MAGB);
      const u64* const myp = blk + lane;
      u64 q;
      u64 qa = __hip_atomic_load(myp, __ATOMIC_RELAXED, __HIP_MEMORY_SCOPE_AGENT);
      u64 qb = __hip_atomic_load(myp, __ATOMIC_RELAXED, __HIP_MEMORY_SCOPE_AGENT);
      for (;;) {
        if (__all(((u32)qa & 0x7FFFu) == want)) { q = qa; break; }
        qa = __hip_atomic_load(myp, __ATOMIC_RELAXED, __HIP_MEMORY_SCOPE_AGENT);
        if (__all(((u32)qb & 0x7FFFu) == want)) { q = qb; break; }
        qb = __hip_atomic_load(myp, __ATOMIC_RELAXED, __HIP_MEMORY_SCOPE_AGENT);
      }
      // max over the 16 key lanes (word==0, lanes 0,4,..,60): xor strides
      // {4,8,16,32} permute that set; others contribute 0
      u64 key = (word == 0) ? q : 0;
      #pragma unroll
      for (int m = 4; m <= 32; m <<= 1) {
        const u64 o = __shfl_xor(key, m, 64);
        if (o > key) key = o;
      }
      const u64 kmax = __shfl(key, 0, 64);         // broadcast winner key
      const unsigned long long ball = __ballot(word == 0 && q == kmax);
      const int wl = __ffsll(ball) - 1;            // winner key lane (=4*slot)
      const u32 hi = (u32)(q >> 32);
      const u32 xb = (u32)__shfl((int)hi, wl + 1, 64);
      const u32 yb = (u32)__shfl((int)hi, wl + 2, 64);
      const u32 zb = (u32)__shfl((int)hi, wl + 3, 64);
      if (lane == 0) {
        s_wx = __uint_as_float(xb);
        s_wy = __uint_as_float(yb);
        s_wz = __uint_as_float(zb);
        if (slot == 0)
          ws_idx[b * KSEL + i + 1] = 131071 - (int)((kmax >> 15) & 0x1FFFFu);
      }
    }
    __syncthreads();                                   // b2: winner ready
    sx = s_wx; sy = s_wy; sz = s_wz;
  }
}

__global__ void gather_kernel(const float* __restrict__ points,
                              const int* __restrict__ ws_idx,
                              float* __restrict__ out) {
  const int e = blockIdx.x * 256 + threadIdx.x;   // 0 .. NB*KSEL*NCH-1
  const int c = e & 15;
  const int k = (e >> 4) & (KSEL - 1);
  const int b = e >> 14;
  const int idx = ws_idx[b * KSEL + k];
  out[e] = points[((size_t)b * NPTS + idx) * NCH + c];
}

extern "C" void kernel_launch(void* const* d_in, const int* in_sizes, int n_in,
                              void* d_out, int out_size, void* d_ws, size_t ws_size,
                              hipStream_t stream) {
  const float* points    = (const float*)d_in[0];
  const int*   start_idx = (const int*)d_in[1];
  float*       out       = (float*)d_out;

  u64* cand = (u64*)((char*)d_ws + 4096);
  int* idxl = (int*)((char*)d_ws + 65536);

  // all record words must start tag-invalid (0) every launch (graph-replay safe)
  hipMemsetAsync(cand, 0, 2 * NB * SLOTS * 4 * sizeof(u64), stream);

  fps_kernel<<<NB * SLOTS, TPB, 0, stream>>>(points, start_idx, cand, idxl);
  gather_kernel<<<(NB * KSEL * NCH) / 256, 256, 0, stream>>>(points, idxl, out);
}

// Round 16
// 2845.370 us; speedup vs baseline: 1.8275x; 1.6388x over previous
//
#include <hip/hip_runtime.h>

#define NB    16      // batches
#define NPTS  100000  // points per batch
#define NCH   16      // channels
#define KSEL  1024    // samples
#define SLOTS 16      // blocks per batch
#define TPB   256     // threads per block
#define CHUNK 6250    // NPTS / SLOTS
#define PPT   25      // CHUNK / TPB
#define MAGA  0x19u   // 5-bit magic, key words    (never 0, never 0xAA-pattern)
#define MAGB  0x13u   // 5-bit magic, payload words

typedef unsigned long long u64;
typedef unsigned int u32;

// ===== r8 structure, reverted verbatim (best: 2870 us) =====
// d_ws layout (bytes):
//   [4096, 20480)  : records u64[par=2][NB][word=4][slot=16]
//                    word 0 = keys line, 1/2/3 = x/y/z lines (128B each)
//   [65536, 131072): idx list int[NB][KSEL]
//
// key     = val_bits(32) | invidx(17) | tag(10) | MAGA(5)   (u64 max == winner)
// payload = coord_bits(32) | invidx(17) | tag(10) | MAGB(5)
// invidx = 131071 - idx (max invidx == min idx -> first-index tie-break).
// tag = i+1 (1..1023, never 0 -> memset-0 / 0xAA never match). Tag+magic in
// EVERY u64 -> stale/torn/poison self-rejecting. Single writer per
// (slot,parity,tag); parity double-buffer prevents i/i+2 overwrite (a slot can
// only advance 2 iterations after ALL slots consumed the current one).
// Contention design: ONE polling wave per block -> 16 pollers per line;
// poll = 1 u64 agent load per lane + s_sleep backoff (measured equilibrium:
// faster sampling (r15) and slower topologies (r9/r10) both regress).

__device__ __forceinline__ void combine(float ov, int oi, float& v, int& i) {
  if (ov > v || (ov == v && oi < i)) { v = ov; i = oi; }
}

__global__ __launch_bounds__(TPB, 1)
void fps_kernel(const float* __restrict__ points, const int* __restrict__ start_idx,
                u64* __restrict__ ws_cand, int* __restrict__ ws_idx) {
  // XCD-affinity swizzle: all 16 blocks of a batch at raw%8==const.
  const int raw  = blockIdx.x;
  const int xcd  = raw & 7;
  const int s    = raw >> 3;
  const int b    = xcd + 8 * (s >> 4);
  const int slot = s & 15;

  const int tid  = threadIdx.x;
  const int lane = tid & 63;
  const int wid  = tid >> 6;

  const int base = slot * CHUNK;
  const float* __restrict__ pb = points + (size_t)b * NPTS * NCH;

  // ---- load xyz into registers, init min_d ----
  float px[PPT], py[PPT], pz[PPT], md[PPT];
  #pragma unroll
  for (int k = 0; k < PPT; ++k) {
    const int li = tid + (k << 8);
    const bool valid = li < CHUNK;
    float4 p = make_float4(0.f, 0.f, 0.f, 0.f);
    if (valid) p = *reinterpret_cast<const float4*>(pb + (size_t)(base + li) * NCH);
    px[k] = p.x; py[k] = p.y; pz[k] = p.z;
    md[k] = valid ? __builtin_inff() : -__builtin_inff();
  }
  #pragma unroll
  for (int k = 0; k < PPT; ++k)   // keep-live guard
    asm volatile("" : "+v"(px[k]), "+v"(py[k]), "+v"(pz[k]), "+v"(md[k]));

  __shared__ float s_rv[4];    // per-wave candidates (written pre-b1, read post-b1)
  __shared__ int   s_ri[4];
  __shared__ float s_wx, s_wy, s_wz;  // winner broadcast (written pre-b2, read post-b2)

  // ---- initial selected point ----
  const int sidx = start_idx[b];
  float sx, sy, sz;
  {
    const float4 p = *reinterpret_cast<const float4*>(pb + (size_t)sidx * NCH);
    sx = p.x; sy = p.y; sz = p.z;
  }
  if (slot == 0 && tid == 0) ws_idx[b * KSEL] = sidx;

  for (int i = 0; i < KSEL - 1; ++i) {
    const int par = i & 1;
    u64* const blk = ws_cand + (((size_t)par * NB + b) << 6);  // 64 u64 per (par,b)

    // ---- distance update + thread-local argmax (bit-exact vs numpy f32:
    //      IEEE intrinsics, left-to-right sum, no FMA contraction) ----
    float bv = -__builtin_inff();
    int   bi = 0x7fffffff;
    #pragma unroll
    for (int k = 0; k < PPT; ++k) {
      const float dx = __fsub_rn(px[k], sx);
      const float dy = __fsub_rn(py[k], sy);
      const float dz = __fsub_rn(pz[k], sz);
      const float d  = __fadd_rn(__fadd_rn(__fmul_rn(dx, dx), __fmul_rn(dy, dy)),
                                 __fmul_rn(dz, dz));
      const float m  = fminf(md[k], d);
      md[k] = m;
      if (m > bv) { bv = m; bi = base + tid + (k << 8); }  // k asc -> first-max kept
    }

    // ---- wave reduce (val, idx), first-index tie-break ----
    #pragma unroll
    for (int m = 32; m >= 1; m >>= 1) {
      const float ov = __shfl_xor(bv, m, 64);
      const int   oi = __shfl_xor(bi, m, 64);
      combine(ov, oi, bv, bi);
    }
    if (lane == 0) { s_rv[wid] = bv; s_ri[wid] = bi; }
    __syncthreads();                                   // b1: candidates ready

    // ---- block combine (every thread) ----
    bv = s_rv[0]; bi = s_ri[0];
    #pragma unroll
    for (int w = 1; w < 4; ++w) combine(s_rv[w], s_ri[w], bv, bi);

    const u32 tm = (u32)(i + 1) << 5;

    // ---- owner thread publishes {key,x,y,z} to the 4 SoA lines ----
    const int local = bi - base;
    if (tid == (local & 255)) {
      const int kk = local >> 8;
      float ox = 0.f, oy = 0.f, oz = 0.f;
      #pragma unroll
      for (int k = 0; k < PPT; ++k)   // static-index select (arrays stay in VGPRs)
        if (k == kk) { ox = px[k]; oy = py[k]; oz = pz[k]; }
      const u32 inv  = 131071u - (u32)bi;
      const u32 loA  = (inv << 15) | tm | MAGA;
      const u32 loB  = (inv << 15) | tm | MAGB;
      __hip_atomic_store(blk      + slot, ((u64)__float_as_uint(bv) << 32) | loA,
                         __ATOMIC_RELAXED, __HIP_MEMORY_SCOPE_AGENT);
      __hip_atomic_store(blk + 16 + slot, ((u64)__float_as_uint(ox) << 32) | loB,
                         __ATOMIC_RELAXED, __HIP_MEMORY_SCOPE_AGENT);
      __hip_atomic_store(blk + 32 + slot, ((u64)__float_as_uint(oy) << 32) | loB,
                         __ATOMIC_RELAXED, __HIP_MEMORY_SCOPE_AGENT);
      __hip_atomic_store(blk + 48 + slot, ((u64)__float_as_uint(oz) << 32) | loB,
                         __ATOMIC_RELAXED, __HIP_MEMORY_SCOPE_AGENT);
    }

    // ---- wave 0 ONLY polls (16 pollers per line) ----
    if (wid == 0) {
      const int wrd = lane >> 4;                 // 0=key,1=x,2=y,3=z
      const u64* const myp = blk + lane;         // [word][slot] layout: blk+lane
      const u32 want = tm | (wrd == 0 ? MAGA : MAGB);
      u64 q;
      for (;;) {
        q = __hip_atomic_load(myp, __ATOMIC_RELAXED, __HIP_MEMORY_SCOPE_AGENT);
        if (__all(((u32)q & 0x7FFFu) == want)) break;
        __builtin_amdgcn_s_sleep(1);
      }
      // max over the 16 key lanes (xor net stays within each 16-group)
      u64 key = q;
      #pragma unroll
      for (int m = 8; m >= 1; m >>= 1) {
        const u64 o = __shfl_xor(key, m, 64);
        if (o > key) key = o;
      }
      const u64 kmax = __shfl(key, 0, 64);       // true key max, broadcast
      const unsigned long long ball = __ballot(wrd == 0 && q == kmax);
      const int rs = __ffsll(ball) - 1;          // winning slot (keys unique)
      const u32 xb = (u32)__shfl((int)(u32)(q >> 32), 16 + rs, 64);
      const u32 yb = (u32)__shfl((int)(u32)(q >> 32), 32 + rs, 64);
      const u32 zb = (u32)__shfl((int)(u32)(q >> 32), 48 + rs, 64);
      if (lane == 0) {
        s_wx = __uint_as_float(xb);
        s_wy = __uint_as_float(yb);
        s_wz = __uint_as_float(zb);
        if (slot == 0)
          ws_idx[b * KSEL + i + 1] = 131071 - (int)((kmax >> 15) & 0x1FFFFu);
      }
    }
    __syncthreads();                                   // b2: winner ready
    sx = s_wx; sy = s_wy; sz = s_wz;
  }
}

__global__ void gather_kernel(const float* __restrict__ points,
                              const int* __restrict__ ws_idx,
                              float* __restrict__ out) {
  const int e = blockIdx.x * TPB + threadIdx.x;   // 0 .. NB*KSEL*NCH-1
  const int c = e & 15;
  const int k = (e >> 4) & (KSEL - 1);
  const int b = e >> 14;
  const int idx = ws_idx[b * KSEL + k];
  out[e] = points[((size_t)b * NPTS + idx) * NCH + c];
}

extern "C" void kernel_launch(void* const* d_in, const int* in_sizes, int n_in,
                              void* d_out, int out_size, void* d_ws, size_t ws_size,
                              hipStream_t stream) {
  const float* points    = (const float*)d_in[0];
  const int*   start_idx = (const int*)d_in[1];
  float*       out       = (float*)d_out;

  u64* cand = (u64*)((char*)d_ws + 4096);
  int* idxl = (int*)((char*)d_ws + 65536);

  // all record words must start tag-invalid (0) every launch (graph-replay safe)
  hipMemsetAsync(cand, 0, 2 * NB * 4 * SLOTS * sizeof(u64), stream);

  fps_kernel<<<NB * SLOTS, TPB, 0, stream>>>(points, start_idx, cand, idxl);
  gather_kernel<<<(NB * KSEL * NCH) / TPB, TPB, 0, stream>>>(points, idxl, out);
}